// Round 6
// baseline (447.209 us; speedup 1.0000x reference)
//
#include <hip/hip_runtime.h>
#include <hip/hip_bf16.h>
#include <cstdint>
#include <cstddef>

#define B_    16
#define LQ    30
#define LD    1100
#define DIM   768
#define NH    12
#define DH_   64
#define WINSZ 11
#define WNUM  100
#define NSLOT 32              // 2 docs x 16 batches

typedef __attribute__((ext_vector_type(8))) short short8;
typedef __attribute__((ext_vector_type(4))) float f32x4;

__device__ __forceinline__ void gload_lds16(const void* g, void* l) {
  __builtin_amdgcn_global_load_lds(
      (const __attribute__((address_space(1))) void*)g,
      (__attribute__((address_space(3))) void*)l, 16, 0, 0);
}

#define MEMFENCE asm volatile("" ::: "memory")

// ---------------------------------------------------------------------------
// weights fp32 -> bf16 (once per launch)
// ---------------------------------------------------------------------------
__global__ __launch_bounds__(256) void wconv_kernel(const float* __restrict__ wa,
    const float* __restrict__ wb, __hip_bfloat16* __restrict__ oa,
    __hip_bfloat16* __restrict__ ob) {
  int i = (blockIdx.x * 256 + threadIdx.x) * 4;
  if (i >= DIM * DIM) return;
  float4 va = *reinterpret_cast<const float4*>(wa + i);
  float4 vb = *reinterpret_cast<const float4*>(wb + i);
  union { __hip_bfloat16 h[4]; uint2 u; } pa, pb;
  pa.h[0] = __float2bfloat16(va.x); pa.h[1] = __float2bfloat16(va.y);
  pa.h[2] = __float2bfloat16(va.z); pa.h[3] = __float2bfloat16(va.w);
  pb.h[0] = __float2bfloat16(vb.x); pb.h[1] = __float2bfloat16(vb.y);
  pb.h[2] = __float2bfloat16(vb.z); pb.h[3] = __float2bfloat16(vb.w);
  *reinterpret_cast<uint2*>(oa + i) = pa.u;
  *reinterpret_cast<uint2*>(ob + i) = pb.u;
}

// ---------------------------------------------------------------------------
// prep_q: Xq[row, e] = bf16( emb[q[row], e] * q_mask[row] * 0.125 )
// ---------------------------------------------------------------------------
__global__ __launch_bounds__(256) void prep_q_kernel(const int* __restrict__ q,
    const float* __restrict__ qmask, const float* __restrict__ emb,
    __hip_bfloat16* __restrict__ Xq) {
  int idx = blockIdx.x * 256 + threadIdx.x;        // 480 * 192 quads
  if (idx >= B_ * LQ * (DIM / 4)) return;
  int row = idx / (DIM / 4);
  int c4  = idx % (DIM / 4);
  float m = qmask[row] * 0.125f;
  float4 v = *reinterpret_cast<const float4*>(emb + (size_t)q[row] * DIM + c4 * 4);
  union { __hip_bfloat16 h[4]; uint2 u; } o;
  o.h[0] = __float2bfloat16(v.x * m); o.h[1] = __float2bfloat16(v.y * m);
  o.h[2] = __float2bfloat16(v.z * m); o.h[3] = __float2bfloat16(v.w * m);
  *reinterpret_cast<uint2*>(Xq + (size_t)row * DIM + c4 * 4) = o.u;
}

// ---------------------------------------------------------------------------
// prep_d (both docs): slot s = s0 + r/LD, doc = s>>4, b = s&15, t = r%LD.
// X[r,e] = bf16( (emb[tok,e]*sqrt(D) + pe[t,e]) * mask )   (pe if flag)
// ---------------------------------------------------------------------------
__global__ __launch_bounds__(256) void prep_d_kernel(const int* __restrict__ dpos,
    const int* __restrict__ dneg, const float* __restrict__ dpmask,
    const float* __restrict__ dnmask, const float* __restrict__ emb,
    const int* __restrict__ peflag, __hip_bfloat16* __restrict__ X,
    int s0, int rows) {
  int idx = blockIdx.x * 256 + threadIdx.x;        // rows * 192 quads
  if (idx >= rows * (DIM / 4)) return;
  int r  = idx / (DIM / 4);
  int c4 = idx % (DIM / 4);
  int s = s0 + r / LD;
  int t = r % LD;
  int doc = s >> 4, b = s & 15;
  const int*   di = doc ? dneg   : dpos;
  const float* dm = doc ? dnmask : dpmask;
  int grow = b * LD + t;
  float m = dm[grow];
  float4 v = *reinterpret_cast<const float4*>(emb + (size_t)di[grow] * DIM + c4 * 4);
  if (peflag[0]) {
    int i0 = c4 * 2;                               // pair indices i0, i0+1
    float d0 = expf(-0.023985261387f * (float)i0);
    float d1 = expf(-0.023985261387f * (float)(i0 + 1));
    float s0f, c0f, s1f, c1f;
    sincosf((float)t * d0, &s0f, &c0f);
    sincosf((float)t * d1, &s1f, &c1f);
    v.x = v.x * 27.712812921102035f + s0f;
    v.y = v.y * 27.712812921102035f + c0f;
    v.z = v.z * 27.712812921102035f + s1f;
    v.w = v.w * 27.712812921102035f + c1f;
  }
  union { __hip_bfloat16 h[4]; uint2 u; } o;
  o.h[0] = __float2bfloat16(v.x * m); o.h[1] = __float2bfloat16(v.y * m);
  o.h[2] = __float2bfloat16(v.z * m); o.h[3] = __float2bfloat16(v.w * m);
  *reinterpret_cast<uint2*>(X + (size_t)r * DIM + c4 * 4) = o.u;
}

// ---------------------------------------------------------------------------
// gemm_mfma: C[M,N] = A[M,K](bf16) @ Bt[N,K](bf16)^T, fp32 accum.
// 128x128 tile, BK=32, 4 waves (2x2), mfma_f32_16x16x32_bf16,
// global_load_lds(16B) staging, TRIPLE-buffered depth-2 pipeline with
// COUNTED vmcnt (T4): stage tile t+2, wait vmcnt(8) (tile t done; t+1,t+2
// stay in flight across barriers), raw s_barrier, COMPUTE(t), trailing
// s_barrier (WAR gate before buf reuse). Epilogue drains 8->4->0.
// K multiple of 32, K/32 >= 3. XCD-swizzled 1D grid. A/Bt tile-padded rows.
// ---------------------------------------------------------------------------
template <bool OUT_BF16>
__global__ __launch_bounds__(256) void gemm_mfma(const __hip_bfloat16* __restrict__ A,
    const __hip_bfloat16* __restrict__ Bt, void* __restrict__ Cv,
    int M, int N, int K, int tilesX) {
  __shared__ __hip_bfloat16 As[3 * 128 * 32];   // 24 KB
  __shared__ __hip_bfloat16 Bs[3 * 128 * 32];   // 24 KB
  const int nwg  = gridDim.x;
  const int orig = blockIdx.x;
  const int q8 = nwg >> 3, r8 = nwg & 7;
  const int xcd = orig & 7, pos = orig >> 3;
  const int wgid = (xcd < r8 ? xcd * (q8 + 1) : r8 * (q8 + 1) + (xcd - r8) * q8) + pos;
  const int row0 = (wgid / tilesX) * 128;
  const int col0 = (wgid % tilesX) * 128;

  const int tid  = threadIdx.x;
  const int lane = tid & 63;
  const int wave = tid >> 6;
  const int wr = wave >> 1, wc = wave & 1;
  const int srow = tid >> 2, skoff = (tid & 3) * 8;

  f32x4 acc[4][4] = {};

  const __hip_bfloat16* gA = A  + (size_t)(row0 + srow) * K + skoff;
  const __hip_bfloat16* gB = Bt + (size_t)(col0 + srow) * K + skoff;

  auto STAGE = [&](int buf, int t) {
    const int k0 = t * 32;
    const int lo = buf * 4096;
    gload_lds16(gA + k0,                  As + lo + tid * 8);
    gload_lds16(gA + (size_t)64 * K + k0, As + lo + 2048 + tid * 8);
    gload_lds16(gB + k0,                  Bs + lo + tid * 8);
    gload_lds16(gB + (size_t)64 * K + k0, Bs + lo + 2048 + tid * 8);
  };
  auto COMPUTE = [&](int buf) {
    const int lo = buf * 4096;
    short8 afrag[4], bfrag[4];
#pragma unroll
    for (int m = 0; m < 4; ++m)
      afrag[m] = *reinterpret_cast<const short8*>(
          &As[lo + (wr * 64 + m * 16 + (lane & 15)) * 32 + (lane >> 4) * 8]);
#pragma unroll
    for (int n = 0; n < 4; ++n)
      bfrag[n] = *reinterpret_cast<const short8*>(
          &Bs[lo + (wc * 64 + n * 16 + (lane & 15)) * 32 + (lane >> 4) * 8]);
#pragma unroll
    for (int m = 0; m < 4; ++m)
#pragma unroll
      for (int n = 0; n < 4; ++n)
        acc[m][n] = __builtin_amdgcn_mfma_f32_16x16x32_bf16(
            afrag[m], bfrag[n], acc[m][n], 0, 0, 0);
  };

  const int nt = K / 32;            // 24 for K=768
  STAGE(0, 0);
  STAGE(1, 1);
  int sb = 2, cb = 0;
  for (int t = 0; t < nt - 2; ++t) {
    STAGE(sb, t + 2);
    sb = (sb == 2) ? 0 : sb + 1;
    asm volatile("s_waitcnt vmcnt(8)" ::: "memory");   // tile t landed; t+1,t+2 in flight
    __builtin_amdgcn_s_barrier();
    MEMFENCE;
    COMPUTE(cb);
    MEMFENCE;
    __builtin_amdgcn_s_barrier();                      // WAR gate: cb readable done
    MEMFENCE;
    cb = (cb == 2) ? 0 : cb + 1;
  }
  asm volatile("s_waitcnt vmcnt(4)" ::: "memory");
  __builtin_amdgcn_s_barrier();
  MEMFENCE;
  COMPUTE(cb);
  cb = (cb == 2) ? 0 : cb + 1;
  asm volatile("s_waitcnt vmcnt(0)" ::: "memory");
  __builtin_amdgcn_s_barrier();
  MEMFENCE;
  COMPUTE(cb);

#pragma unroll
  for (int m = 0; m < 4; ++m) {
    int rb = row0 + wr * 64 + m * 16 + (lane >> 4) * 4;
#pragma unroll
    for (int n = 0; n < 4; ++n) {
      int c = col0 + wc * 64 + n * 16 + (lane & 15);
      f32x4 v = acc[m][n];
#pragma unroll
      for (int j = 0; j < 4; ++j) {
        int r = rb + j;
        if (r < M) {
          if constexpr (OUT_BF16)
            ((__hip_bfloat16*)Cv)[(size_t)r * N + c] = __float2bfloat16(v[j]);
          else
            ((float*)Cv)[(size_t)r * N + c] = v[j];
        }
      }
    }
  }
}

// ---------------------------------------------------------------------------
// attn: one block per (slot_local, w, h), 120 threads = 30 qi x 4 part.
// Q segment in registers from global (L2-hot); D staged in LDS fp32
// (broadcast float4 reads, conflict-free); shfl_xor partial-dot reduce.
// ---------------------------------------------------------------------------
__global__ __launch_bounds__(128) void attn_kernel(const float* __restrict__ Qs,
    const __hip_bfloat16* __restrict__ Y, __hip_bfloat16* __restrict__ ctx, int s0) {
  int blk = blockIdx.x;
  int h  = blk % NH;
  int w  = (blk / NH) % WNUM;
  int sl = blk / (NH * WNUM);
  int b  = (s0 + sl) & 15;          // batch index (doc-independent Q)

  __shared__ float Dl[WINSZ][DH_];

  const __hip_bfloat16* Yb = Y + ((size_t)(sl * LD + w * WINSZ)) * DIM + h * (WINSZ * DH_);
  const float* Qb = Qs + (size_t)b * (LQ * DIM) + h * (LQ * DH_);

  int tid = threadIdx.x;
  int qi = tid >> 2, part = tid & 3;

  if (tid < 88) {
    uint4 raw = *reinterpret_cast<const uint4*>(Yb + tid * 8);
    const __hip_bfloat16* hp = reinterpret_cast<const __hip_bfloat16*>(&raw);
    float* dst = &Dl[0][0] + tid * 8;
#pragma unroll
    for (int j = 0; j < 8; ++j) dst[j] = __bfloat162float(hp[j]);
  }

  float4 qreg[4];
#pragma unroll
  for (int j = 0; j < 4; ++j)
    qreg[j] = *reinterpret_cast<const float4*>(Qb + qi * DH_ + part * 16 + j * 4);
  __syncthreads();

  float dot[WINSZ];
#pragma unroll
  for (int k = 0; k < WINSZ; ++k) {
    const float4* dp = reinterpret_cast<const float4*>(&Dl[k][part * 16]);
    float s = 0.f;
#pragma unroll
    for (int j = 0; j < 4; ++j) {
      float4 dv = dp[j];
      s += qreg[j].x * dv.x + qreg[j].y * dv.y + qreg[j].z * dv.z + qreg[j].w * dv.w;
    }
    dot[k] = s;
  }
#pragma unroll
  for (int k = 0; k < WINSZ; ++k) {
    dot[k] += __shfl_xor(dot[k], 1);
    dot[k] += __shfl_xor(dot[k], 2);
  }
  float mx = -1e30f;
#pragma unroll
  for (int k = 0; k < WINSZ; ++k) mx = fmaxf(mx, dot[k]);
  float sum = 0.f;
#pragma unroll
  for (int k = 0; k < WINSZ; ++k) { dot[k] = expf(dot[k] - mx); sum += dot[k]; }
  float inv = 1.f / sum;

  float4 o[4] = {};
#pragma unroll
  for (int k = 0; k < WINSZ; ++k) {
    float pk = dot[k];
    const float4* dp = reinterpret_cast<const float4*>(&Dl[k][part * 16]);
#pragma unroll
    for (int j = 0; j < 4; ++j) {
      float4 dv = dp[j];
      o[j].x += pk * dv.x; o[j].y += pk * dv.y;
      o[j].z += pk * dv.z; o[j].w += pk * dv.w;
    }
  }
  union { __hip_bfloat16 hh[16]; uint4 v[2]; } pk;
#pragma unroll
  for (int j = 0; j < 4; ++j) {
    pk.hh[j * 4 + 0] = __float2bfloat16(o[j].x * inv);
    pk.hh[j * 4 + 1] = __float2bfloat16(o[j].y * inv);
    pk.hh[j * 4 + 2] = __float2bfloat16(o[j].z * inv);
    pk.hh[j * 4 + 3] = __float2bfloat16(o[j].w * inv);
  }
  __hip_bfloat16* op = ctx + (size_t)(sl * WNUM + w) * (LQ * DIM)
                     + h * (LQ * DH_) + qi * DH_ + part * 16;
  *reinterpret_cast<uint4*>(op)     = pk.v[0];
  *reinterpret_cast<uint4*>(op + 8) = pk.v[1];
}

// ---------------------------------------------------------------------------
extern "C" void kernel_launch(void* const* d_in, const int* in_sizes, int n_in,
                              void* d_out, int out_size, void* d_ws, size_t ws_size,
                              hipStream_t stream) {
  const int*   q      = (const int*)d_in[0];
  const int*   dpos   = (const int*)d_in[1];
  const int*   dneg   = (const int*)d_in[2];
  const float* qmask  = (const float*)d_in[3];
  const float* dpmask = (const float*)d_in[4];
  const float* dnmask = (const float*)d_in[5];
  const int*   peflag = (const int*)d_in[6];
  const float* emb    = (const float*)d_in[7];
  const float* Wlin   = (const float*)d_in[8];
  const float* Wout   = (const float*)d_in[9];
  float* out = (float*)d_out;

  char* ws = (char*)d_ws;
  size_t off = 0;
  auto alloc = [&](size_t bytes) -> char* {
    char* p = ws + off; off += (bytes + 255) & ~(size_t)255; return p;
  };
  __hip_bfloat16* Xq   = (__hip_bfloat16*)alloc((size_t)B_ * LQ * DIM * 2);
  float*          Qsc  = (float*)         alloc((size_t)B_ * LQ * DIM * 4);
  __hip_bfloat16* Wl16 = (__hip_bfloat16*)alloc((size_t)DIM * DIM * 2);
  __hip_bfloat16* Wo16 = (__hip_bfloat16*)alloc((size_t)DIM * DIM * 2);

  // slots per chunk: all 32 (both docs) if ws allows; else halve.
  // buffers tile-padded (+128 rows) so gemm A-overreads stay in-bounds.
  int SC = NSLOT;
  while (SC > 1) {
    size_t need = off
        + ((size_t)SC * LD + 128) * DIM * 2 * 2                 // X + Y
        + ((size_t)SC * WNUM * LQ + 128) * DIM * 2 + (1u << 20);// ctx
    if (need <= ws_size) break;
    SC >>= 1;
  }
  __hip_bfloat16* X   = (__hip_bfloat16*)alloc(((size_t)SC * LD + 128) * DIM * 2);
  __hip_bfloat16* Y   = (__hip_bfloat16*)alloc(((size_t)SC * LD + 128) * DIM * 2);
  __hip_bfloat16* ctx = (__hip_bfloat16*)alloc(((size_t)SC * WNUM * LQ + 128) * DIM * 2);

  wconv_kernel<<<(DIM * DIM / 4 + 255) / 256, 256, 0, stream>>>(Wlin, Wout, Wl16, Wo16);
  prep_q_kernel<<<(B_ * LQ * (DIM / 4) + 255) / 256, 256, 0, stream>>>(q, qmask, emb, Xq);
  {
    int tilesX = DIM / 128, tilesY = (B_ * LQ + 127) / 128;
    gemm_mfma<false><<<tilesX * tilesY, 256, 0, stream>>>(
        Xq, Wl16, Qsc, B_ * LQ, DIM, DIM, tilesX);
  }

  for (int s0 = 0; s0 < NSLOT; s0 += SC) {
    const int rowsX = SC * LD;           // 35200 at SC=32
    const int rowsC = SC * WNUM * LQ;    // 96000 at SC=32
    prep_d_kernel<<<(rowsX * (DIM / 4) + 255) / 256, 256, 0, stream>>>(
        dpos, dneg, dpmask, dnmask, emb, peflag, X, s0, rowsX);
    {
      int tilesX = DIM / 128, tilesY = (rowsX + 127) / 128;
      gemm_mfma<true><<<tilesX * tilesY, 256, 0, stream>>>(
          X, Wl16, Y, rowsX, DIM, DIM, tilesX);
    }
    attn_kernel<<<SC * WNUM * NH, 120, 0, stream>>>(Qsc, Y, ctx, s0);
    {
      int tilesX = DIM / 128, tilesY = (rowsC + 127) / 128;
      gemm_mfma<false><<<tilesX * tilesY, 256, 0, stream>>>(
          ctx, Wo16, out + (size_t)s0 * WNUM * LQ * DIM, rowsC, DIM, DIM, tilesX);
    }
  }
}

// Round 7
// 420.879 us; speedup vs baseline: 1.0626x; 1.0626x over previous
//
#include <hip/hip_runtime.h>
#include <hip/hip_bf16.h>
#include <cstdint>
#include <cstddef>

#define B_    16
#define LQ    30
#define LD    1100
#define DIM   768
#define NH    12
#define DH_   64
#define WINSZ 11
#define WNUM  100
#define NSLOT 32              // 2 docs x 16 batches

typedef __attribute__((ext_vector_type(8))) short short8;
typedef __attribute__((ext_vector_type(4))) float f32x4;

__device__ __forceinline__ void gload_lds16(const void* g, void* l) {
  __builtin_amdgcn_global_load_lds(
      (const __attribute__((address_space(1))) void*)g,
      (__attribute__((address_space(3))) void*)l, 16, 0, 0);
}

// ---------------------------------------------------------------------------
// weights fp32 -> bf16 (once per launch)
// ---------------------------------------------------------------------------
__global__ __launch_bounds__(256) void wconv_kernel(const float* __restrict__ wa,
    const float* __restrict__ wb, __hip_bfloat16* __restrict__ oa,
    __hip_bfloat16* __restrict__ ob) {
  int i = (blockIdx.x * 256 + threadIdx.x) * 4;
  if (i >= DIM * DIM) return;
  float4 va = *reinterpret_cast<const float4*>(wa + i);
  float4 vb = *reinterpret_cast<const float4*>(wb + i);
  union { __hip_bfloat16 h[4]; uint2 u; } pa, pb;
  pa.h[0] = __float2bfloat16(va.x); pa.h[1] = __float2bfloat16(va.y);
  pa.h[2] = __float2bfloat16(va.z); pa.h[3] = __float2bfloat16(va.w);
  pb.h[0] = __float2bfloat16(vb.x); pb.h[1] = __float2bfloat16(vb.y);
  pb.h[2] = __float2bfloat16(vb.z); pb.h[3] = __float2bfloat16(vb.w);
  *reinterpret_cast<uint2*>(oa + i) = pa.u;
  *reinterpret_cast<uint2*>(ob + i) = pb.u;
}

// ---------------------------------------------------------------------------
// prep_q: Xq[row, e] = bf16( emb[q[row], e] * q_mask[row] * 0.125 )
// ---------------------------------------------------------------------------
__global__ __launch_bounds__(256) void prep_q_kernel(const int* __restrict__ q,
    const float* __restrict__ qmask, const float* __restrict__ emb,
    __hip_bfloat16* __restrict__ Xq) {
  int idx = blockIdx.x * 256 + threadIdx.x;        // 480 * 192 quads
  if (idx >= B_ * LQ * (DIM / 4)) return;
  int row = idx / (DIM / 4);
  int c4  = idx % (DIM / 4);
  float m = qmask[row] * 0.125f;
  float4 v = *reinterpret_cast<const float4*>(emb + (size_t)q[row] * DIM + c4 * 4);
  union { __hip_bfloat16 h[4]; uint2 u; } o;
  o.h[0] = __float2bfloat16(v.x * m); o.h[1] = __float2bfloat16(v.y * m);
  o.h[2] = __float2bfloat16(v.z * m); o.h[3] = __float2bfloat16(v.w * m);
  *reinterpret_cast<uint2*>(Xq + (size_t)row * DIM + c4 * 4) = o.u;
}

// ---------------------------------------------------------------------------
// prep_d (both docs): slot s = s0 + r/LD, doc = s>>4, b = s&15, t = r%LD.
// X[r,e] = bf16( (emb[tok,e]*sqrt(D) + pe[t,e]) * mask )   (pe if flag)
// ---------------------------------------------------------------------------
__global__ __launch_bounds__(256) void prep_d_kernel(const int* __restrict__ dpos,
    const int* __restrict__ dneg, const float* __restrict__ dpmask,
    const float* __restrict__ dnmask, const float* __restrict__ emb,
    const int* __restrict__ peflag, __hip_bfloat16* __restrict__ X,
    int s0, int rows) {
  int idx = blockIdx.x * 256 + threadIdx.x;        // rows * 192 quads
  if (idx >= rows * (DIM / 4)) return;
  int r  = idx / (DIM / 4);
  int c4 = idx % (DIM / 4);
  int s = s0 + r / LD;
  int t = r % LD;
  int doc = s >> 4, b = s & 15;
  const int*   di = doc ? dneg   : dpos;
  const float* dm = doc ? dnmask : dpmask;
  int grow = b * LD + t;
  float m = dm[grow];
  float4 v = *reinterpret_cast<const float4*>(emb + (size_t)di[grow] * DIM + c4 * 4);
  if (peflag[0]) {
    int i0 = c4 * 2;                               // pair indices i0, i0+1
    float d0 = expf(-0.023985261387f * (float)i0);
    float d1 = expf(-0.023985261387f * (float)(i0 + 1));
    float s0f, c0f, s1f, c1f;
    sincosf((float)t * d0, &s0f, &c0f);
    sincosf((float)t * d1, &s1f, &c1f);
    v.x = v.x * 27.712812921102035f + s0f;
    v.y = v.y * 27.712812921102035f + c0f;
    v.z = v.z * 27.712812921102035f + s1f;
    v.w = v.w * 27.712812921102035f + c1f;
  }
  union { __hip_bfloat16 h[4]; uint2 u; } o;
  o.h[0] = __float2bfloat16(v.x * m); o.h[1] = __float2bfloat16(v.y * m);
  o.h[2] = __float2bfloat16(v.z * m); o.h[3] = __float2bfloat16(v.w * m);
  *reinterpret_cast<uint2*>(X + (size_t)r * DIM + c4 * 4) = o.u;
}

// ---------------------------------------------------------------------------
// gemm_mfma: C[M,N] = A[M,K](bf16) @ Bt[N,K](bf16)^T, fp32 accum.
// 256x256 tile, BK=32, 512 thr = 8 waves (2Mx4N, per-wave 128x64 out).
// 4 LDS buffers (128 KB dynamic), stage-ahead-3 with COUNTED vmcnt(8)
// (never 0 in main loop) + ONE barrier per iteration.
//   RAW: vmcnt(8)+barrier => tile t landed in all waves before reads.
//   WAR: STAGE(t+3) hits buf (t-1)&3, issued after the barrier that follows
//        all waves' tile-(t-1) reads (reads complete before their MFMAs).
// T2 chunk-XOR swizzle, both-sides (rule #21): staging pre-swizzles the
// GLOBAL source chunk (LDS dest linear for global_load_lds); reads apply the
// same involution -> 2 lanes/bank (free) instead of 8-way conflicts.
// K multiple of 32, K/32 >= 4. N multiple of 256. Rows tile-padded for reads;
// stores guarded by r < M.
// ---------------------------------------------------------------------------
template <bool OUT_BF16>
__global__ __launch_bounds__(512, 2) void gemm_mfma(const __hip_bfloat16* __restrict__ A,
    const __hip_bfloat16* __restrict__ Bt, void* __restrict__ Cv,
    int M, int N, int K, int tilesX) {
  extern __shared__ __hip_bfloat16 smem[];
  __hip_bfloat16* As = smem;                 // 4 bufs x 8192 elems (16 KB each)
  __hip_bfloat16* Bs = smem + 4 * 8192;

  const int nwg  = gridDim.x;
  const int orig = blockIdx.x;
  const int q8 = nwg >> 3, r8 = nwg & 7;
  const int xcd = orig & 7, pos = orig >> 3;
  const int wgid = (xcd < r8 ? xcd * (q8 + 1) : r8 * (q8 + 1) + (xcd - r8) * q8) + pos;
  const int row0 = (wgid / tilesX) * 256;
  const int col0 = (wgid % tilesX) * 256;

  const int tid  = threadIdx.x;
  const int lane = tid & 63;
  const int wave = tid >> 6;
  const int wr = wave >> 2, wc = wave & 3;     // 2 x 4 waves
  const int lo4 = lane & 15;

  // staging: thread covers rows (tid>>2) and 128+(tid>>2), chunk tid&3.
  // pre-swizzled global chunk (involution with the read-side XOR):
  const int csrc = (tid & 3) ^ ((tid >> 3) & 3);
  const __hip_bfloat16* gA = A  + (size_t)(row0 + (tid >> 2)) * K + csrc * 8;
  const __hip_bfloat16* gB = Bt + (size_t)(col0 + (tid >> 2)) * K + csrc * 8;

  // read-side: swizzled chunk elem offset (same for all frags of this lane)
  const int coff = (((lane >> 4) ^ ((lo4 >> 1) & 3)) * 8);
  const int arow = (wr * 128 + lo4) * 32 + coff;   // +m*512 per A-frag
  const int brow = (wc * 64  + lo4) * 32 + coff;   // +n*512 per B-frag

  f32x4 acc[8][4] = {};

  auto STAGE = [&](int tt) {
    const int k0 = tt * 32;
    const int lo = (tt & 3) * 8192;
    gload_lds16(gA + k0,                   As + lo + tid * 8);
    gload_lds16(gA + (size_t)128 * K + k0, As + lo + 4096 + tid * 8);
    gload_lds16(gB + k0,                   Bs + lo + tid * 8);
    gload_lds16(gB + (size_t)128 * K + k0, Bs + lo + 4096 + tid * 8);
  };

#define STEP(tt, WAITN, DOSTAGE)                                        \
  {                                                                     \
    asm volatile("s_waitcnt vmcnt(" WAITN ")" ::: "memory");            \
    __builtin_amdgcn_s_barrier();                                       \
    __builtin_amdgcn_sched_barrier(0);                                  \
    const int lo = ((tt) & 3) * 8192;                                   \
    short8 af[8]; short8 bq[4];                                         \
    const __hip_bfloat16* Ab = As + lo + arow;                          \
    const __hip_bfloat16* Bb = Bs + lo + brow;                          \
    _Pragma("unroll")                                                   \
    for (int m = 0; m < 8; ++m)                                         \
      af[m] = *reinterpret_cast<const short8*>(Ab + m * 512);           \
    _Pragma("unroll")                                                   \
    for (int n = 0; n < 4; ++n)                                         \
      bq[n] = *reinterpret_cast<const short8*>(Bb + n * 512);           \
    if (DOSTAGE) STAGE((tt) + 3);                                       \
    __builtin_amdgcn_s_setprio(1);                                      \
    _Pragma("unroll")                                                   \
    for (int m = 0; m < 8; ++m)                                         \
      _Pragma("unroll")                                                 \
      for (int n = 0; n < 4; ++n)                                       \
        acc[m][n] = __builtin_amdgcn_mfma_f32_16x16x32_bf16(            \
            af[m], bq[n], acc[m][n], 0, 0, 0);                          \
    __builtin_amdgcn_s_setprio(0);                                      \
  }

  const int nt = K / 32;            // 24 for K=768
  STAGE(0); STAGE(1); STAGE(2);     // 12 loads in flight
  for (int t = 0; t < nt - 3; ++t)
    STEP(t, "8", true)              // retire tile t; keep t+1..t+3 in flight
  STEP(nt - 3, "8", false)
  STEP(nt - 2, "4", false)
  STEP(nt - 1, "0", false)
#undef STEP

#pragma unroll
  for (int m = 0; m < 8; ++m) {
    int rb = row0 + wr * 128 + m * 16 + (lane >> 4) * 4;
#pragma unroll
    for (int n = 0; n < 4; ++n) {
      int c = col0 + wc * 64 + n * 16 + lo4;
      f32x4 v = acc[m][n];
#pragma unroll
      for (int j = 0; j < 4; ++j) {
        int r = rb + j;
        if (r < M) {
          if constexpr (OUT_BF16)
            ((__hip_bfloat16*)Cv)[(size_t)r * N + c] = __float2bfloat16(v[j]);
          else
            ((float*)Cv)[(size_t)r * N + c] = v[j];
        }
      }
    }
  }
}

// ---------------------------------------------------------------------------
// attn: one block per (slot_local, w, h), 120 threads = 30 qi x 4 part.
// Q segment in registers from global (L2-hot); D staged in LDS fp32
// (broadcast float4 reads, conflict-free); shfl_xor partial-dot reduce.
// ---------------------------------------------------------------------------
__global__ __launch_bounds__(128) void attn_kernel(const float* __restrict__ Qs,
    const __hip_bfloat16* __restrict__ Y, __hip_bfloat16* __restrict__ ctx, int s0) {
  int blk = blockIdx.x;
  int h  = blk % NH;
  int w  = (blk / NH) % WNUM;
  int sl = blk / (NH * WNUM);
  int b  = (s0 + sl) & 15;          // batch index (doc-independent Q)

  __shared__ float Dl[WINSZ][DH_];

  const __hip_bfloat16* Yb = Y + ((size_t)(sl * LD + w * WINSZ)) * DIM + h * (WINSZ * DH_);
  const float* Qb = Qs + (size_t)b * (LQ * DIM) + h * (LQ * DH_);

  int tid = threadIdx.x;
  int qi = tid >> 2, part = tid & 3;

  if (tid < 88) {
    uint4 raw = *reinterpret_cast<const uint4*>(Yb + tid * 8);
    const __hip_bfloat16* hp = reinterpret_cast<const __hip_bfloat16*>(&raw);
    float* dst = &Dl[0][0] + tid * 8;
#pragma unroll
    for (int j = 0; j < 8; ++j) dst[j] = __bfloat162float(hp[j]);
  }

  float4 qreg[4];
#pragma unroll
  for (int j = 0; j < 4; ++j)
    qreg[j] = *reinterpret_cast<const float4*>(Qb + qi * DH_ + part * 16 + j * 4);
  __syncthreads();

  float dot[WINSZ];
#pragma unroll
  for (int k = 0; k < WINSZ; ++k) {
    const float4* dp = reinterpret_cast<const float4*>(&Dl[k][part * 16]);
    float s = 0.f;
#pragma unroll
    for (int j = 0; j < 4; ++j) {
      float4 dv = dp[j];
      s += qreg[j].x * dv.x + qreg[j].y * dv.y + qreg[j].z * dv.z + qreg[j].w * dv.w;
    }
    dot[k] = s;
  }
#pragma unroll
  for (int k = 0; k < WINSZ; ++k) {
    dot[k] += __shfl_xor(dot[k], 1);
    dot[k] += __shfl_xor(dot[k], 2);
  }
  float mx = -1e30f;
#pragma unroll
  for (int k = 0; k < WINSZ; ++k) mx = fmaxf(mx, dot[k]);
  float sum = 0.f;
#pragma unroll
  for (int k = 0; k < WINSZ; ++k) { dot[k] = expf(dot[k] - mx); sum += dot[k]; }
  float inv = 1.f / sum;

  float4 o[4] = {};
#pragma unroll
  for (int k = 0; k < WINSZ; ++k) {
    float pk = dot[k];
    const float4* dp = reinterpret_cast<const float4*>(&Dl[k][part * 16]);
#pragma unroll
    for (int j = 0; j < 4; ++j) {
      float4 dv = dp[j];
      o[j].x += pk * dv.x; o[j].y += pk * dv.y;
      o[j].z += pk * dv.z; o[j].w += pk * dv.w;
    }
  }
  union { __hip_bfloat16 hh[16]; uint4 v[2]; } pk;
#pragma unroll
  for (int j = 0; j < 4; ++j) {
    pk.hh[j * 4 + 0] = __float2bfloat16(o[j].x * inv);
    pk.hh[j * 4 + 1] = __float2bfloat16(o[j].y * inv);
    pk.hh[j * 4 + 2] = __float2bfloat16(o[j].z * inv);
    pk.hh[j * 4 + 3] = __float2bfloat16(o[j].w * inv);
  }
  __hip_bfloat16* op = ctx + (size_t)(sl * WNUM + w) * (LQ * DIM)
                     + h * (LQ * DH_) + qi * DH_ + part * 16;
  *reinterpret_cast<uint4*>(op)     = pk.v[0];
  *reinterpret_cast<uint4*>(op + 8) = pk.v[1];
}

// ---------------------------------------------------------------------------
extern "C" void kernel_launch(void* const* d_in, const int* in_sizes, int n_in,
                              void* d_out, int out_size, void* d_ws, size_t ws_size,
                              hipStream_t stream) {
  const int*   q      = (const int*)d_in[0];
  const int*   dpos   = (const int*)d_in[1];
  const int*   dneg   = (const int*)d_in[2];
  const float* qmask  = (const float*)d_in[3];
  const float* dpmask = (const float*)d_in[4];
  const float* dnmask = (const float*)d_in[5];
  const int*   peflag = (const int*)d_in[6];
  const float* emb    = (const float*)d_in[7];
  const float* Wlin   = (const float*)d_in[8];
  const float* Wout   = (const float*)d_in[9];
  float* out = (float*)d_out;

  // allow 128 KB dynamic LDS (first call is uncaptured; attribute persists)
  (void)hipFuncSetAttribute(reinterpret_cast<const void*>(&gemm_mfma<false>),
                            hipFuncAttributeMaxDynamicSharedMemorySize, 131072);
  (void)hipFuncSetAttribute(reinterpret_cast<const void*>(&gemm_mfma<true>),
                            hipFuncAttributeMaxDynamicSharedMemorySize, 131072);

  char* ws = (char*)d_ws;
  size_t off = 0;
  auto alloc = [&](size_t bytes) -> char* {
    char* p = ws + off; off += (bytes + 255) & ~(size_t)255; return p;
  };
  __hip_bfloat16* Xq   = (__hip_bfloat16*)alloc((size_t)512 * DIM * 2);  // 480 rows + tile pad
  float*          Qsc  = (float*)         alloc((size_t)B_ * LQ * DIM * 4);
  __hip_bfloat16* Wl16 = (__hip_bfloat16*)alloc((size_t)DIM * DIM * 2);
  __hip_bfloat16* Wo16 = (__hip_bfloat16*)alloc((size_t)DIM * DIM * 2);

  // slots per chunk: all 32 (both docs) if ws allows; else halve.
  // buffers tile-padded (+256 rows) so gemm A-overreads stay in-bounds.
  int SC = NSLOT;
  while (SC > 1) {
    size_t need = off
        + ((size_t)SC * LD + 256) * DIM * 2 * 2                 // X + Y
        + ((size_t)SC * WNUM * LQ + 256) * DIM * 2 + (1u << 20);// ctx
    if (need <= ws_size) break;
    SC >>= 1;
  }
  __hip_bfloat16* X   = (__hip_bfloat16*)alloc(((size_t)SC * LD + 256) * DIM * 2);
  __hip_bfloat16* Y   = (__hip_bfloat16*)alloc(((size_t)SC * LD + 256) * DIM * 2);
  __hip_bfloat16* ctx = (__hip_bfloat16*)alloc(((size_t)SC * WNUM * LQ + 256) * DIM * 2);

  wconv_kernel<<<(DIM * DIM / 4 + 255) / 256, 256, 0, stream>>>(Wlin, Wout, Wl16, Wo16);
  prep_q_kernel<<<(B_ * LQ * (DIM / 4) + 255) / 256, 256, 0, stream>>>(q, qmask, emb, Xq);
  {
    int tilesX = DIM / 256, tilesY = (B_ * LQ + 255) / 256;
    gemm_mfma<false><<<tilesX * tilesY, 512, 131072, stream>>>(
        Xq, Wl16, Qsc, B_ * LQ, DIM, DIM, tilesX);
  }

  for (int s0 = 0; s0 < NSLOT; s0 += SC) {
    const int rowsX = SC * LD;           // 35200 at SC=32
    const int rowsC = SC * WNUM * LQ;    // 96000 at SC=32
    prep_d_kernel<<<(rowsX * (DIM / 4) + 255) / 256, 256, 0, stream>>>(
        dpos, dneg, dpmask, dnmask, emb, peflag, X, s0, rowsX);
    {
      int tilesX = DIM / 256, tilesY = (rowsX + 255) / 256;
      gemm_mfma<true><<<tilesX * tilesY, 512, 131072, stream>>>(
          X, Wl16, Y, rowsX, DIM, DIM, tilesX);
    }
    attn_kernel<<<SC * WNUM * NH, 120, 0, stream>>>(Qsc, Y, ctx, s0);
    {
      int tilesX = DIM / 256, tilesY = (rowsC + 255) / 256;
      gemm_mfma<false><<<tilesX * tilesY, 512, 131072, stream>>>(
          ctx, Wo16, out + (size_t)s0 * WNUM * LQ * DIM, rowsC, DIM, DIM, tilesX);
    }
  }
}

// Round 8
// 399.670 us; speedup vs baseline: 1.1189x; 1.0531x over previous
//
#include <hip/hip_runtime.h>
#include <hip/hip_bf16.h>
#include <cstdint>
#include <cstddef>

#define B_    16
#define LQ    30
#define LD    1100
#define DIM   768
#define NH    12
#define DH_   64
#define WINSZ 11
#define WNUM  100
#define NSLOT 32              // 2 docs x 16 batches

typedef __attribute__((ext_vector_type(8))) short short8;
typedef __attribute__((ext_vector_type(4))) float f32x4;

__device__ __forceinline__ void gload_lds16(const void* g, void* l) {
  __builtin_amdgcn_global_load_lds(
      (const __attribute__((address_space(1))) void*)g,
      (__attribute__((address_space(3))) void*)l, 16, 0, 0);
}

// ---------------------------------------------------------------------------
// weights fp32 -> bf16 (once per launch)
// ---------------------------------------------------------------------------
__global__ __launch_bounds__(256) void wconv_kernel(const float* __restrict__ wa,
    const float* __restrict__ wb, __hip_bfloat16* __restrict__ oa,
    __hip_bfloat16* __restrict__ ob) {
  int i = (blockIdx.x * 256 + threadIdx.x) * 4;
  if (i >= DIM * DIM) return;
  float4 va = *reinterpret_cast<const float4*>(wa + i);
  float4 vb = *reinterpret_cast<const float4*>(wb + i);
  union { __hip_bfloat16 h[4]; uint2 u; } pa, pb;
  pa.h[0] = __float2bfloat16(va.x); pa.h[1] = __float2bfloat16(va.y);
  pa.h[2] = __float2bfloat16(va.z); pa.h[3] = __float2bfloat16(va.w);
  pb.h[0] = __float2bfloat16(vb.x); pb.h[1] = __float2bfloat16(vb.y);
  pb.h[2] = __float2bfloat16(vb.z); pb.h[3] = __float2bfloat16(vb.w);
  *reinterpret_cast<uint2*>(oa + i) = pa.u;
  *reinterpret_cast<uint2*>(ob + i) = pb.u;
}

// ---------------------------------------------------------------------------
// prep_q: Xq[row, e] = bf16( emb[q[row], e] * q_mask[row] * 0.125 )
// ---------------------------------------------------------------------------
__global__ __launch_bounds__(256) void prep_q_kernel(const int* __restrict__ q,
    const float* __restrict__ qmask, const float* __restrict__ emb,
    __hip_bfloat16* __restrict__ Xq) {
  int idx = blockIdx.x * 256 + threadIdx.x;        // 480 * 192 quads
  if (idx >= B_ * LQ * (DIM / 4)) return;
  int row = idx / (DIM / 4);
  int c4  = idx % (DIM / 4);
  float m = qmask[row] * 0.125f;
  float4 v = *reinterpret_cast<const float4*>(emb + (size_t)q[row] * DIM + c4 * 4);
  union { __hip_bfloat16 h[4]; uint2 u; } o;
  o.h[0] = __float2bfloat16(v.x * m); o.h[1] = __float2bfloat16(v.y * m);
  o.h[2] = __float2bfloat16(v.z * m); o.h[3] = __float2bfloat16(v.w * m);
  *reinterpret_cast<uint2*>(Xq + (size_t)row * DIM + c4 * 4) = o.u;
}

// ---------------------------------------------------------------------------
// prep_d (both docs): slot s = s0 + r/LD, doc = s>>4, b = s&15, t = r%LD.
// X[r,e] = bf16( (emb[tok,e]*sqrt(D) + pe[t,e]) * mask )   (pe if flag)
// ---------------------------------------------------------------------------
__global__ __launch_bounds__(256) void prep_d_kernel(const int* __restrict__ dpos,
    const int* __restrict__ dneg, const float* __restrict__ dpmask,
    const float* __restrict__ dnmask, const float* __restrict__ emb,
    const int* __restrict__ peflag, __hip_bfloat16* __restrict__ X,
    int s0, int rows) {
  int idx = blockIdx.x * 256 + threadIdx.x;        // rows * 192 quads
  if (idx >= rows * (DIM / 4)) return;
  int r  = idx / (DIM / 4);
  int c4 = idx % (DIM / 4);
  int s = s0 + r / LD;
  int t = r % LD;
  int doc = s >> 4, b = s & 15;
  const int*   di = doc ? dneg   : dpos;
  const float* dm = doc ? dnmask : dpmask;
  int grow = b * LD + t;
  float m = dm[grow];
  float4 v = *reinterpret_cast<const float4*>(emb + (size_t)di[grow] * DIM + c4 * 4);
  if (peflag[0]) {
    int i0 = c4 * 2;                               // pair indices i0, i0+1
    float d0 = expf(-0.023985261387f * (float)i0);
    float d1 = expf(-0.023985261387f * (float)(i0 + 1));
    float s0f, c0f, s1f, c1f;
    sincosf((float)t * d0, &s0f, &c0f);
    sincosf((float)t * d1, &s1f, &c1f);
    v.x = v.x * 27.712812921102035f + s0f;
    v.y = v.y * 27.712812921102035f + c0f;
    v.z = v.z * 27.712812921102035f + s1f;
    v.w = v.w * 27.712812921102035f + c1f;
  }
  union { __hip_bfloat16 h[4]; uint2 u; } o;
  o.h[0] = __float2bfloat16(v.x * m); o.h[1] = __float2bfloat16(v.y * m);
  o.h[2] = __float2bfloat16(v.z * m); o.h[3] = __float2bfloat16(v.w * m);
  *reinterpret_cast<uint2*>(X + (size_t)r * DIM + c4 * 4) = o.u;
}

// ---------------------------------------------------------------------------
// gemm_mfma: C[M,N] = A[M,K](bf16) @ Bt[N,K](bf16)^T, fp32 accum.
// 256x256 tile, BK=32, 512 thr = 8 waves (2Mx4N, per-wave 128x64 out).
// 4 LDS buffers, stage-ahead-3, COUNTED vmcnt(8) once per K-step (never 0 in
// main loop), and the K-step split into TWO PHASES (T3 interleave, m201 shape):
//   Phase 0: vmcnt+barrier | read bq[0..3]+af[0..3] | stage A-halves(t+3)
//            | lgkmcnt(0) | setprio | 16 MFMA (m0-3)
//   Phase 1: barrier | read af[4..7] | stage B-halves(t+3)
//            | lgkmcnt(0) | setprio | 16 MFMA (m4-7)
// RAW: vmcnt(8)+barrier => tile t landed before any wave reads it.
// WAR: stages of step t target buf (t-1)&3; every wave's reads of that buf
//      were consumed (lgkmcnt(0)) before the barrier that precedes the stage.
// Per-wave stage issue order [A0,A1,B0,B1] preserved => vmcnt math as R7.
// T2 chunk-XOR swizzle both-sides (rule #21), verified R7 (conflicts = 0).
// K multiple of 32, K/32 >= 4. N multiple of 256. Rows tile-padded for reads;
// stores guarded by r < M.
// ---------------------------------------------------------------------------
template <bool OUT_BF16>
__global__ __launch_bounds__(512, 2) void gemm_mfma(const __hip_bfloat16* __restrict__ A,
    const __hip_bfloat16* __restrict__ Bt, void* __restrict__ Cv,
    int M, int N, int K, int tilesX) {
  extern __shared__ __hip_bfloat16 smem[];
  __hip_bfloat16* As = smem;                 // 4 bufs x 8192 elems (16 KB each)
  __hip_bfloat16* Bs = smem + 4 * 8192;

  const int nwg  = gridDim.x;
  const int orig = blockIdx.x;
  const int q8 = nwg >> 3, r8 = nwg & 7;
  const int xcd = orig & 7, pos = orig >> 3;
  const int wgid = (xcd < r8 ? xcd * (q8 + 1) : r8 * (q8 + 1) + (xcd - r8) * q8) + pos;
  const int row0 = (wgid / tilesX) * 256;
  const int col0 = (wgid % tilesX) * 256;

  const int tid  = threadIdx.x;
  const int lane = tid & 63;
  const int wave = tid >> 6;
  const int wr = wave >> 2, wc = wave & 3;     // 2 x 4 waves
  const int lo4 = lane & 15;

  // staging: thread covers rows (tid>>2) and 128+(tid>>2), chunk tid&3.
  // pre-swizzled global chunk (involution with the read-side XOR):
  const int csrc = (tid & 3) ^ ((tid >> 3) & 3);
  const __hip_bfloat16* gA = A  + (size_t)(row0 + (tid >> 2)) * K + csrc * 8;
  const __hip_bfloat16* gB = Bt + (size_t)(col0 + (tid >> 2)) * K + csrc * 8;

  // read-side: swizzled chunk elem offset (same for all frags of this lane)
  const int coff = (((lane >> 4) ^ ((lo4 >> 1) & 3)) * 8);
  const int arow = (wr * 128 + lo4) * 32 + coff;   // +m*512 per A-frag
  const int brow = (wc * 64  + lo4) * 32 + coff;   // +n*512 per B-frag

  f32x4 acc[8][4] = {};

  auto STAGE = [&](int tt) {
    const int k0 = tt * 32;
    const int lo = (tt & 3) * 8192;
    gload_lds16(gA + k0,                   As + lo + tid * 8);
    gload_lds16(gA + (size_t)128 * K + k0, As + lo + 4096 + tid * 8);
    gload_lds16(gB + k0,                   Bs + lo + tid * 8);
    gload_lds16(gB + (size_t)128 * K + k0, Bs + lo + 4096 + tid * 8);
  };

#define MFMA4(MB)                                                       \
    _Pragma("unroll")                                                   \
    for (int n = 0; n < 4; ++n)                                         \
      acc[MB][n] = __builtin_amdgcn_mfma_f32_16x16x32_bf16(             \
          af0, bq[n], acc[MB][n], 0, 0, 0);                             \
    _Pragma("unroll")                                                   \
    for (int n = 0; n < 4; ++n)                                         \
      acc[MB + 1][n] = __builtin_amdgcn_mfma_f32_16x16x32_bf16(         \
          af1, bq[n], acc[MB + 1][n], 0, 0, 0);

#define STEP(tt, WAITN, DOSTAGE)                                        \
  {                                                                     \
    const int lo = ((tt) & 3) * 8192;                                   \
    const int so = (((tt) + 3) & 3) * 8192;                             \
    const int k0s = ((tt) + 3) * 32;                                    \
    const __hip_bfloat16* Ab = As + lo + arow;                          \
    const __hip_bfloat16* Bb = Bs + lo + brow;                          \
    short8 bq[4], af0, af1, af2, af3;                                   \
    /* ---- phase 0 ---- */                                             \
    asm volatile("s_waitcnt vmcnt(" WAITN ")" ::: "memory");            \
    __builtin_amdgcn_s_barrier();                                       \
    __builtin_amdgcn_sched_barrier(0);                                  \
    bq[0] = *reinterpret_cast<const short8*>(Bb);                       \
    bq[1] = *reinterpret_cast<const short8*>(Bb + 512);                 \
    bq[2] = *reinterpret_cast<const short8*>(Bb + 1024);                \
    bq[3] = *reinterpret_cast<const short8*>(Bb + 1536);                \
    af0 = *reinterpret_cast<const short8*>(Ab);                         \
    af1 = *reinterpret_cast<const short8*>(Ab + 512);                   \
    af2 = *reinterpret_cast<const short8*>(Ab + 1024);                  \
    af3 = *reinterpret_cast<const short8*>(Ab + 1536);                  \
    if (DOSTAGE) {                                                      \
      gload_lds16(gA + k0s,                   As + so + tid * 8);       \
      gload_lds16(gA + (size_t)128 * K + k0s, As + so + 4096 + tid * 8);\
    }                                                                   \
    asm volatile("s_waitcnt lgkmcnt(0)" ::: "memory");                  \
    __builtin_amdgcn_sched_barrier(0);                                  \
    __builtin_amdgcn_s_setprio(1);                                      \
    MFMA4(0)                                                            \
    { short8 t0 = af2, t1 = af3; af0 = t0; af1 = t1; }                  \
    MFMA4(2)                                                            \
    __builtin_amdgcn_s_setprio(0);                                      \
    /* ---- phase 1 ---- */                                             \
    __builtin_amdgcn_s_barrier();                                       \
    af0 = *reinterpret_cast<const short8*>(Ab + 2048);                  \
    af1 = *reinterpret_cast<const short8*>(Ab + 2560);                  \
    af2 = *reinterpret_cast<const short8*>(Ab + 3072);                  \
    af3 = *reinterpret_cast<const short8*>(Ab + 3584);                  \
    if (DOSTAGE) {                                                      \
      gload_lds16(gB + k0s,                   Bs + so + tid * 8);       \
      gload_lds16(gB + (size_t)128 * K + k0s, Bs + so + 4096 + tid * 8);\
    }                                                                   \
    asm volatile("s_waitcnt lgkmcnt(0)" ::: "memory");                  \
    __builtin_amdgcn_sched_barrier(0);                                  \
    __builtin_amdgcn_s_setprio(1);                                      \
    MFMA4(4)                                                            \
    { short8 t0 = af2, t1 = af3; af0 = t0; af1 = t1; }                  \
    MFMA4(6)                                                            \
    __builtin_amdgcn_s_setprio(0);                                      \
  }

  const int nt = K / 32;            // 24 for K=768
  STAGE(0); STAGE(1); STAGE(2);     // 12 loads in flight
  for (int t = 0; t < nt - 3; ++t)
    STEP(t, "8", true)              // retire tile t; keep t+1..t+3 in flight
  STEP(nt - 3, "8", false)
  STEP(nt - 2, "4", false)
  STEP(nt - 1, "0", false)
#undef STEP
#undef MFMA4

#pragma unroll
  for (int m = 0; m < 8; ++m) {
    int rb = row0 + wr * 128 + m * 16 + (lane >> 4) * 4;
#pragma unroll
    for (int n = 0; n < 4; ++n) {
      int c = col0 + wc * 64 + n * 16 + lo4;
      f32x4 v = acc[m][n];
#pragma unroll
      for (int j = 0; j < 4; ++j) {
        int r = rb + j;
        if (r < M) {
          if constexpr (OUT_BF16)
            ((__hip_bfloat16*)Cv)[(size_t)r * N + c] = __float2bfloat16(v[j]);
          else
            ((float*)Cv)[(size_t)r * N + c] = v[j];
        }
      }
    }
  }
}

// ---------------------------------------------------------------------------
// attn: one block per (slot_local, w, h), 120 threads = 30 qi x 4 part.
// Q segment in registers from global (L2-hot); D staged in LDS fp32
// (broadcast float4 reads, conflict-free); shfl_xor partial-dot reduce.
// ---------------------------------------------------------------------------
__global__ __launch_bounds__(128) void attn_kernel(const float* __restrict__ Qs,
    const __hip_bfloat16* __restrict__ Y, __hip_bfloat16* __restrict__ ctx, int s0) {
  int blk = blockIdx.x;
  int h  = blk % NH;
  int w  = (blk / NH) % WNUM;
  int sl = blk / (NH * WNUM);
  int b  = (s0 + sl) & 15;          // batch index (doc-independent Q)

  __shared__ float Dl[WINSZ][DH_];

  const __hip_bfloat16* Yb = Y + ((size_t)(sl * LD + w * WINSZ)) * DIM + h * (WINSZ * DH_);
  const float* Qb = Qs + (size_t)b * (LQ * DIM) + h * (LQ * DH_);

  int tid = threadIdx.x;
  int qi = tid >> 2, part = tid & 3;

  if (tid < 88) {
    uint4 raw = *reinterpret_cast<const uint4*>(Yb + tid * 8);
    const __hip_bfloat16* hp = reinterpret_cast<const __hip_bfloat16*>(&raw);
    float* dst = &Dl[0][0] + tid * 8;
#pragma unroll
    for (int j = 0; j < 8; ++j) dst[j] = __bfloat162float(hp[j]);
  }

  float4 qreg[4];
#pragma unroll
  for (int j = 0; j < 4; ++j)
    qreg[j] = *reinterpret_cast<const float4*>(Qb + qi * DH_ + part * 16 + j * 4);
  __syncthreads();

  float dot[WINSZ];
#pragma unroll
  for (int k = 0; k < WINSZ; ++k) {
    const float4* dp = reinterpret_cast<const float4*>(&Dl[k][part * 16]);
    float s = 0.f;
#pragma unroll
    for (int j = 0; j < 4; ++j) {
      float4 dv = dp[j];
      s += qreg[j].x * dv.x + qreg[j].y * dv.y + qreg[j].z * dv.z + qreg[j].w * dv.w;
    }
    dot[k] = s;
  }
#pragma unroll
  for (int k = 0; k < WINSZ; ++k) {
    dot[k] += __shfl_xor(dot[k], 1);
    dot[k] += __shfl_xor(dot[k], 2);
  }
  float mx = -1e30f;
#pragma unroll
  for (int k = 0; k < WINSZ; ++k) mx = fmaxf(mx, dot[k]);
  float sum = 0.f;
#pragma unroll
  for (int k = 0; k < WINSZ; ++k) { dot[k] = expf(dot[k] - mx); sum += dot[k]; }
  float inv = 1.f / sum;

  float4 o[4] = {};
#pragma unroll
  for (int k = 0; k < WINSZ; ++k) {
    float pk = dot[k];
    const float4* dp = reinterpret_cast<const float4*>(&Dl[k][part * 16]);
#pragma unroll
    for (int j = 0; j < 4; ++j) {
      float4 dv = dp[j];
      o[j].x += pk * dv.x; o[j].y += pk * dv.y;
      o[j].z += pk * dv.z; o[j].w += pk * dv.w;
    }
  }
  union { __hip_bfloat16 hh[16]; uint4 v[2]; } pk;
#pragma unroll
  for (int j = 0; j < 4; ++j) {
    pk.hh[j * 4 + 0] = __float2bfloat16(o[j].x * inv);
    pk.hh[j * 4 + 1] = __float2bfloat16(o[j].y * inv);
    pk.hh[j * 4 + 2] = __float2bfloat16(o[j].z * inv);
    pk.hh[j * 4 + 3] = __float2bfloat16(o[j].w * inv);
  }
  __hip_bfloat16* op = ctx + (size_t)(sl * WNUM + w) * (LQ * DIM)
                     + h * (LQ * DH_) + qi * DH_ + part * 16;
  *reinterpret_cast<uint4*>(op)     = pk.v[0];
  *reinterpret_cast<uint4*>(op + 8) = pk.v[1];
}

// ---------------------------------------------------------------------------
extern "C" void kernel_launch(void* const* d_in, const int* in_sizes, int n_in,
                              void* d_out, int out_size, void* d_ws, size_t ws_size,
                              hipStream_t stream) {
  const int*   q      = (const int*)d_in[0];
  const int*   dpos   = (const int*)d_in[1];
  const int*   dneg   = (const int*)d_in[2];
  const float* qmask  = (const float*)d_in[3];
  const float* dpmask = (const float*)d_in[4];
  const float* dnmask = (const float*)d_in[5];
  const int*   peflag = (const int*)d_in[6];
  const float* emb    = (const float*)d_in[7];
  const float* Wlin   = (const float*)d_in[8];
  const float* Wout   = (const float*)d_in[9];
  float* out = (float*)d_out;

  // allow 128 KB dynamic LDS (first call is uncaptured; attribute persists)
  (void)hipFuncSetAttribute(reinterpret_cast<const void*>(&gemm_mfma<false>),
                            hipFuncAttributeMaxDynamicSharedMemorySize, 131072);
  (void)hipFuncSetAttribute(reinterpret_cast<const void*>(&gemm_mfma<true>),
                            hipFuncAttributeMaxDynamicSharedMemorySize, 131072);

  char* ws = (char*)d_ws;
  size_t off = 0;
  auto alloc = [&](size_t bytes) -> char* {
    char* p = ws + off; off += (bytes + 255) & ~(size_t)255; return p;
  };
  __hip_bfloat16* Xq   = (__hip_bfloat16*)alloc((size_t)512 * DIM * 2);  // 480 rows + tile pad
  float*          Qsc  = (float*)         alloc((size_t)B_ * LQ * DIM * 4);
  __hip_bfloat16* Wl16 = (__hip_bfloat16*)alloc((size_t)DIM * DIM * 2);
  __hip_bfloat16* Wo16 = (__hip_bfloat16*)alloc((size_t)DIM * DIM * 2);

  // slots per chunk: all 32 (both docs) if ws allows; else halve.
  // buffers tile-padded (+256 rows) so gemm A-overreads stay in-bounds.
  int SC = NSLOT;
  while (SC > 1) {
    size_t need = off
        + ((size_t)SC * LD + 256) * DIM * 2 * 2                 // X + Y
        + ((size_t)SC * WNUM * LQ + 256) * DIM * 2 + (1u << 20);// ctx
    if (need <= ws_size) break;
    SC >>= 1;
  }
  __hip_bfloat16* X   = (__hip_bfloat16*)alloc(((size_t)SC * LD + 256) * DIM * 2);
  __hip_bfloat16* Y   = (__hip_bfloat16*)alloc(((size_t)SC * LD + 256) * DIM * 2);
  __hip_bfloat16* ctx = (__hip_bfloat16*)alloc(((size_t)SC * WNUM * LQ + 256) * DIM * 2);

  wconv_kernel<<<(DIM * DIM / 4 + 255) / 256, 256, 0, stream>>>(Wlin, Wout, Wl16, Wo16);
  prep_q_kernel<<<(B_ * LQ * (DIM / 4) + 255) / 256, 256, 0, stream>>>(q, qmask, emb, Xq);
  {
    int tilesX = DIM / 256, tilesY = (B_ * LQ + 255) / 256;
    gemm_mfma<false><<<tilesX * tilesY, 512, 131072, stream>>>(
        Xq, Wl16, Qsc, B_ * LQ, DIM, DIM, tilesX);
  }

  for (int s0 = 0; s0 < NSLOT; s0 += SC) {
    const int rowsX = SC * LD;           // 35200 at SC=32
    const int rowsC = SC * WNUM * LQ;    // 96000 at SC=32
    prep_d_kernel<<<(rowsX * (DIM / 4) + 255) / 256, 256, 0, stream>>>(
        dpos, dneg, dpmask, dnmask, emb, peflag, X, s0, rowsX);
    {
      int tilesX = DIM / 256, tilesY = (rowsX + 255) / 256;
      gemm_mfma<true><<<tilesX * tilesY, 512, 131072, stream>>>(
          X, Wl16, Y, rowsX, DIM, DIM, tilesX);
    }
    attn_kernel<<<SC * WNUM * NH, 120, 0, stream>>>(Qsc, Y, ctx, s0);
    {
      int tilesX = DIM / 256, tilesY = (rowsC + 255) / 256;
      gemm_mfma<false><<<tilesX * tilesY, 512, 131072, stream>>>(
          ctx, Wo16, out + (size_t)s0 * WNUM * LQ * DIM, rowsC, DIM, DIM, tilesX);
    }
  }
}

// Round 9
// 385.427 us; speedup vs baseline: 1.1603x; 1.0370x over previous
//
#include <hip/hip_runtime.h>
#include <hip/hip_bf16.h>
#include <cstdint>
#include <cstddef>

#define B_    16
#define LQ    30
#define LD    1100
#define DIM   768
#define NH    12
#define DH_   64
#define WINSZ 11
#define WNUM  100
#define NSLOT 32              // 2 docs x 16 batches

typedef __attribute__((ext_vector_type(8))) short short8;
typedef __attribute__((ext_vector_type(4))) float f32x4;

__device__ __forceinline__ void gload_lds16(const void* g, void* l) {
  __builtin_amdgcn_global_load_lds(
      (const __attribute__((address_space(1))) void*)g,
      (__attribute__((address_space(3))) void*)l, 16, 0, 0);
}

// ---------------------------------------------------------------------------
// weights fp32 -> bf16 (once per launch)
// ---------------------------------------------------------------------------
__global__ __launch_bounds__(256) void wconv_kernel(const float* __restrict__ wa,
    const float* __restrict__ wb, __hip_bfloat16* __restrict__ oa,
    __hip_bfloat16* __restrict__ ob) {
  int i = (blockIdx.x * 256 + threadIdx.x) * 4;
  if (i >= DIM * DIM) return;
  float4 va = *reinterpret_cast<const float4*>(wa + i);
  float4 vb = *reinterpret_cast<const float4*>(wb + i);
  union { __hip_bfloat16 h[4]; uint2 u; } pa, pb;
  pa.h[0] = __float2bfloat16(va.x); pa.h[1] = __float2bfloat16(va.y);
  pa.h[2] = __float2bfloat16(va.z); pa.h[3] = __float2bfloat16(va.w);
  pb.h[0] = __float2bfloat16(vb.x); pb.h[1] = __float2bfloat16(vb.y);
  pb.h[2] = __float2bfloat16(vb.z); pb.h[3] = __float2bfloat16(vb.w);
  *reinterpret_cast<uint2*>(oa + i) = pa.u;
  *reinterpret_cast<uint2*>(ob + i) = pb.u;
}

// ---------------------------------------------------------------------------
// prep_q: Xq[row, e] = bf16( emb[q[row], e] * q_mask[row] * 0.125 )
// ---------------------------------------------------------------------------
__global__ __launch_bounds__(256) void prep_q_kernel(const int* __restrict__ q,
    const float* __restrict__ qmask, const float* __restrict__ emb,
    __hip_bfloat16* __restrict__ Xq) {
  int idx = blockIdx.x * 256 + threadIdx.x;        // 480 * 192 quads
  if (idx >= B_ * LQ * (DIM / 4)) return;
  int row = idx / (DIM / 4);
  int c4  = idx % (DIM / 4);
  float m = qmask[row] * 0.125f;
  float4 v = *reinterpret_cast<const float4*>(emb + (size_t)q[row] * DIM + c4 * 4);
  union { __hip_bfloat16 h[4]; uint2 u; } o;
  o.h[0] = __float2bfloat16(v.x * m); o.h[1] = __float2bfloat16(v.y * m);
  o.h[2] = __float2bfloat16(v.z * m); o.h[3] = __float2bfloat16(v.w * m);
  *reinterpret_cast<uint2*>(Xq + (size_t)row * DIM + c4 * 4) = o.u;
}

// ---------------------------------------------------------------------------
// prep_d (both docs): slot s = s0 + r/LD, doc = s>>4, b = s&15, t = r%LD.
// X[r,e] = bf16( (emb[tok,e]*sqrt(D) + pe[t,e]) * mask )   (pe if flag)
// ---------------------------------------------------------------------------
__global__ __launch_bounds__(256) void prep_d_kernel(const int* __restrict__ dpos,
    const int* __restrict__ dneg, const float* __restrict__ dpmask,
    const float* __restrict__ dnmask, const float* __restrict__ emb,
    const int* __restrict__ peflag, __hip_bfloat16* __restrict__ X,
    int s0, int rows) {
  int idx = blockIdx.x * 256 + threadIdx.x;        // rows * 192 quads
  if (idx >= rows * (DIM / 4)) return;
  int r  = idx / (DIM / 4);
  int c4 = idx % (DIM / 4);
  int s = s0 + r / LD;
  int t = r % LD;
  int doc = s >> 4, b = s & 15;
  const int*   di = doc ? dneg   : dpos;
  const float* dm = doc ? dnmask : dpmask;
  int grow = b * LD + t;
  float m = dm[grow];
  float4 v = *reinterpret_cast<const float4*>(emb + (size_t)di[grow] * DIM + c4 * 4);
  if (peflag[0]) {
    int i0 = c4 * 2;                               // pair indices i0, i0+1
    float d0 = expf(-0.023985261387f * (float)i0);
    float d1 = expf(-0.023985261387f * (float)(i0 + 1));
    float s0f, c0f, s1f, c1f;
    sincosf((float)t * d0, &s0f, &c0f);
    sincosf((float)t * d1, &s1f, &c1f);
    v.x = v.x * 27.712812921102035f + s0f;
    v.y = v.y * 27.712812921102035f + c0f;
    v.z = v.z * 27.712812921102035f + s1f;
    v.w = v.w * 27.712812921102035f + c1f;
  }
  union { __hip_bfloat16 h[4]; uint2 u; } o;
  o.h[0] = __float2bfloat16(v.x * m); o.h[1] = __float2bfloat16(v.y * m);
  o.h[2] = __float2bfloat16(v.z * m); o.h[3] = __float2bfloat16(v.w * m);
  *reinterpret_cast<uint2*>(X + (size_t)r * DIM + c4 * 4) = o.u;
}

// ---------------------------------------------------------------------------
// gemm_mfma: C[M,N] = A[M,K](bf16) @ Bt[N,K](bf16)^T, fp32 accum.
// 256x256 tile, BK=32, 512 thr = 8 waves (2Mx4N, per-wave 128x64 out).
// Pipeline identical to R8 (verified): 4 LDS bufs, stage-ahead-3, counted
// vmcnt(8), 2-phase interleave, T2 chunk-XOR swizzle both-sides.
// NEW vs R8:
//  (a) OPERAND-SWAP MFMA: acc = mfma(bq, af, acc). Element value is the
//      identical dot product (transposed placement), so reg j walks
//      consecutive C-COLUMNS -> float4 / packed-bf16x4 stores (4x fewer
//      store insts, 16B/8B per lane instead of 4B/2B).
//  (b) DUAL-PROBLEM grid: blocks with wgid >= tiles1 compute problem 2
//      (A2[M2,K] @ Bt -> C2 fp32) -- used to fold the tiny Q-GEMM into the
//      GEMM1 launch so its blocks run concurrently instead of serially.
// K multiple of 32, K/32 >= 4. N multiple of 256. Rows tile-padded for reads;
// stores guarded by r < M.
// ---------------------------------------------------------------------------
template <bool OUT_BF16>
__global__ __launch_bounds__(512, 2) void gemm_mfma(const __hip_bfloat16* __restrict__ A,
    const __hip_bfloat16* __restrict__ Bt, void* __restrict__ Cv,
    int M, int N, int K, int tilesX, int tiles1,
    const __hip_bfloat16* __restrict__ A2, float* __restrict__ C2, int M2) {
  extern __shared__ __hip_bfloat16 smem[];
  __hip_bfloat16* As = smem;                 // 4 bufs x 8192 elems (16 KB each)
  __hip_bfloat16* Bs = smem + 4 * 8192;

  const int nwg  = gridDim.x;
  const int orig = blockIdx.x;
  const int q8 = nwg >> 3, r8 = nwg & 7;
  const int xcd = orig & 7, pos = orig >> 3;
  const int wgid = (xcd < r8 ? xcd * (q8 + 1) : r8 * (q8 + 1) + (xcd - r8) * q8) + pos;

  const bool is2 = (wgid >= tiles1);
  const int  w2  = is2 ? (wgid - tiles1) : wgid;
  const int row0 = (w2 / tilesX) * 256;
  const int col0 = (w2 % tilesX) * 256;
  const __hip_bfloat16* Ap = is2 ? A2 : A;
  const int Mloc = is2 ? M2 : M;

  const int tid  = threadIdx.x;
  const int lane = tid & 63;
  const int wave = tid >> 6;
  const int wr = wave >> 2, wc = wave & 3;     // 2 x 4 waves
  const int lo4 = lane & 15;
  const int hi4 = lane >> 4;

  // staging: thread covers rows (tid>>2) and 128+(tid>>2), chunk tid&3.
  // pre-swizzled global chunk (involution with the read-side XOR):
  const int csrc = (tid & 3) ^ ((tid >> 3) & 3);
  const __hip_bfloat16* gA = Ap + (size_t)(row0 + (tid >> 2)) * K + csrc * 8;
  const __hip_bfloat16* gB = Bt + (size_t)(col0 + (tid >> 2)) * K + csrc * 8;

  // read-side: swizzled chunk elem offset (same for all frags of this lane)
  const int coff = ((hi4 ^ ((lo4 >> 1) & 3)) * 8);
  const int arow = (wr * 128 + lo4) * 32 + coff;   // +m*512 per A-frag
  const int brow = (wc * 64  + lo4) * 32 + coff;   // +n*512 per B-frag

  f32x4 acc[8][4] = {};

  auto STAGE = [&](int tt) {
    const int k0 = tt * 32;
    const int lo = (tt & 3) * 8192;
    gload_lds16(gA + k0,                   As + lo + tid * 8);
    gload_lds16(gA + (size_t)128 * K + k0, As + lo + 4096 + tid * 8);
    gload_lds16(gB + k0,                   Bs + lo + tid * 8);
    gload_lds16(gB + (size_t)128 * K + k0, Bs + lo + 4096 + tid * 8);
  };

#define MFMA4(MB)                                                       \
    _Pragma("unroll")                                                   \
    for (int n = 0; n < 4; ++n)                                         \
      acc[MB][n] = __builtin_amdgcn_mfma_f32_16x16x32_bf16(             \
          bq[n], af0, acc[MB][n], 0, 0, 0);                             \
    _Pragma("unroll")                                                   \
    for (int n = 0; n < 4; ++n)                                         \
      acc[MB + 1][n] = __builtin_amdgcn_mfma_f32_16x16x32_bf16(         \
          bq[n], af1, acc[MB + 1][n], 0, 0, 0);

#define STEP(tt, WAITN, DOSTAGE)                                        \
  {                                                                     \
    const int lo = ((tt) & 3) * 8192;                                   \
    const int so = (((tt) + 3) & 3) * 8192;                             \
    const int k0s = ((tt) + 3) * 32;                                    \
    const __hip_bfloat16* Ab = As + lo + arow;                          \
    const __hip_bfloat16* Bb = Bs + lo + brow;                          \
    short8 bq[4], af0, af1, af2, af3;                                   \
    /* ---- phase 0 ---- */                                             \
    asm volatile("s_waitcnt vmcnt(" WAITN ")" ::: "memory");            \
    __builtin_amdgcn_s_barrier();                                       \
    __builtin_amdgcn_sched_barrier(0);                                  \
    bq[0] = *reinterpret_cast<const short8*>(Bb);                       \
    bq[1] = *reinterpret_cast<const short8*>(Bb + 512);                 \
    bq[2] = *reinterpret_cast<const short8*>(Bb + 1024);                \
    bq[3] = *reinterpret_cast<const short8*>(Bb + 1536);                \
    af0 = *reinterpret_cast<const short8*>(Ab);                         \
    af1 = *reinterpret_cast<const short8*>(Ab + 512);                   \
    af2 = *reinterpret_cast<const short8*>(Ab + 1024);                  \
    af3 = *reinterpret_cast<const short8*>(Ab + 1536);                  \
    if (DOSTAGE) {                                                      \
      gload_lds16(gA + k0s,                   As + so + tid * 8);       \
      gload_lds16(gA + (size_t)128 * K + k0s, As + so + 4096 + tid * 8);\
    }                                                                   \
    asm volatile("s_waitcnt lgkmcnt(0)" ::: "memory");                  \
    __builtin_amdgcn_sched_barrier(0);                                  \
    __builtin_amdgcn_s_setprio(1);                                      \
    MFMA4(0)                                                            \
    { short8 t0 = af2, t1 = af3; af0 = t0; af1 = t1; }                  \
    MFMA4(2)                                                            \
    __builtin_amdgcn_s_setprio(0);                                      \
    /* ---- phase 1 ---- */                                             \
    __builtin_amdgcn_s_barrier();                                       \
    af0 = *reinterpret_cast<const short8*>(Ab + 2048);                  \
    af1 = *reinterpret_cast<const short8*>(Ab + 2560);                  \
    af2 = *reinterpret_cast<const short8*>(Ab + 3072);                  \
    af3 = *reinterpret_cast<const short8*>(Ab + 3584);                  \
    if (DOSTAGE) {                                                      \
      gload_lds16(gB + k0s,                   Bs + so + tid * 8);       \
      gload_lds16(gB + (size_t)128 * K + k0s, Bs + so + 4096 + tid * 8);\
    }                                                                   \
    asm volatile("s_waitcnt lgkmcnt(0)" ::: "memory");                  \
    __builtin_amdgcn_sched_barrier(0);                                  \
    __builtin_amdgcn_s_setprio(1);                                      \
    MFMA4(4)                                                            \
    { short8 t0 = af2, t1 = af3; af0 = t0; af1 = t1; }                  \
    MFMA4(6)                                                            \
    __builtin_amdgcn_s_setprio(0);                                      \
  }

  const int nt = K / 32;            // 24 for K=768
  STAGE(0); STAGE(1); STAGE(2);     // 12 loads in flight
  for (int t = 0; t < nt - 3; ++t)
    STEP(t, "8", true)              // retire tile t; keep t+1..t+3 in flight
  STEP(nt - 3, "8", false)
  STEP(nt - 2, "4", false)
  STEP(nt - 1, "0", false)
#undef STEP
#undef MFMA4

  // epilogue (swapped layout): lane holds C[row = ..+lo4][col = ..+hi4*4+j]
  // -> reg j walks consecutive columns: vectorized stores.
#pragma unroll
  for (int m = 0; m < 8; ++m) {
    const int r = row0 + wr * 128 + m * 16 + lo4;
    if (r < Mloc) {
#pragma unroll
      for (int n = 0; n < 4; ++n) {
        const int cb = col0 + wc * 64 + n * 16 + hi4 * 4;
        f32x4 v = acc[m][n];
        if (is2) {
          *reinterpret_cast<f32x4*>(C2 + (size_t)r * N + cb) = v;
        } else if constexpr (OUT_BF16) {
          union { __hip_bfloat16 h[4]; uint2 u; } p;
          p.h[0] = __float2bfloat16(v[0]); p.h[1] = __float2bfloat16(v[1]);
          p.h[2] = __float2bfloat16(v[2]); p.h[3] = __float2bfloat16(v[3]);
          *reinterpret_cast<uint2*>((__hip_bfloat16*)Cv + (size_t)r * N + cb) = p.u;
        } else {
          *reinterpret_cast<f32x4*>((float*)Cv + (size_t)r * N + cb) = v;
        }
      }
    }
  }
}

// ---------------------------------------------------------------------------
// attn: one block per (slot_local, w, h), 120 threads = 30 qi x 4 part.
// Q segment in registers from global (L2-hot); D staged in LDS fp32
// (broadcast float4 reads, conflict-free); shfl_xor partial-dot reduce.
// ---------------------------------------------------------------------------
__global__ __launch_bounds__(128) void attn_kernel(const float* __restrict__ Qs,
    const __hip_bfloat16* __restrict__ Y, __hip_bfloat16* __restrict__ ctx, int s0) {
  int blk = blockIdx.x;
  int h  = blk % NH;
  int w  = (blk / NH) % WNUM;
  int sl = blk / (NH * WNUM);
  int b  = (s0 + sl) & 15;          // batch index (doc-independent Q)

  __shared__ float Dl[WINSZ][DH_];

  const __hip_bfloat16* Yb = Y + ((size_t)(sl * LD + w * WINSZ)) * DIM + h * (WINSZ * DH_);
  const float* Qb = Qs + (size_t)b * (LQ * DIM) + h * (LQ * DH_);

  int tid = threadIdx.x;
  int qi = tid >> 2, part = tid & 3;

  if (tid < 88) {
    uint4 raw = *reinterpret_cast<const uint4*>(Yb + tid * 8);
    const __hip_bfloat16* hp = reinterpret_cast<const __hip_bfloat16*>(&raw);
    float* dst = &Dl[0][0] + tid * 8;
#pragma unroll
    for (int j = 0; j < 8; ++j) dst[j] = __bfloat162float(hp[j]);
  }

  float4 qreg[4];
#pragma unroll
  for (int j = 0; j < 4; ++j)
    qreg[j] = *reinterpret_cast<const float4*>(Qb + qi * DH_ + part * 16 + j * 4);
  __syncthreads();

  float dot[WINSZ];
#pragma unroll
  for (int k = 0; k < WINSZ; ++k) {
    const float4* dp = reinterpret_cast<const float4*>(&Dl[k][part * 16]);
    float s = 0.f;
#pragma unroll
    for (int j = 0; j < 4; ++j) {
      float4 dv = dp[j];
      s += qreg[j].x * dv.x + qreg[j].y * dv.y + qreg[j].z * dv.z + qreg[j].w * dv.w;
    }
    dot[k] = s;
  }
#pragma unroll
  for (int k = 0; k < WINSZ; ++k) {
    dot[k] += __shfl_xor(dot[k], 1);
    dot[k] += __shfl_xor(dot[k], 2);
  }
  float mx = -1e30f;
#pragma unroll
  for (int k = 0; k < WINSZ; ++k) mx = fmaxf(mx, dot[k]);
  float sum = 0.f;
#pragma unroll
  for (int k = 0; k < WINSZ; ++k) { dot[k] = expf(dot[k] - mx); sum += dot[k]; }
  float inv = 1.f / sum;

  float4 o[4] = {};
#pragma unroll
  for (int k = 0; k < WINSZ; ++k) {
    float pk = dot[k];
    const float4* dp = reinterpret_cast<const float4*>(&Dl[k][part * 16]);
#pragma unroll
    for (int j = 0; j < 4; ++j) {
      float4 dv = dp[j];
      o[j].x += pk * dv.x; o[j].y += pk * dv.y;
      o[j].z += pk * dv.z; o[j].w += pk * dv.w;
    }
  }
  union { __hip_bfloat16 hh[16]; uint4 v[2]; } pk;
#pragma unroll
  for (int j = 0; j < 4; ++j) {
    pk.hh[j * 4 + 0] = __float2bfloat16(o[j].x * inv);
    pk.hh[j * 4 + 1] = __float2bfloat16(o[j].y * inv);
    pk.hh[j * 4 + 2] = __float2bfloat16(o[j].z * inv);
    pk.hh[j * 4 + 3] = __float2bfloat16(o[j].w * inv);
  }
  __hip_bfloat16* op = ctx + (size_t)(sl * WNUM + w) * (LQ * DIM)
                     + h * (LQ * DH_) + qi * DH_ + part * 16;
  *reinterpret_cast<uint4*>(op)     = pk.v[0];
  *reinterpret_cast<uint4*>(op + 8) = pk.v[1];
}

// ---------------------------------------------------------------------------
extern "C" void kernel_launch(void* const* d_in, const int* in_sizes, int n_in,
                              void* d_out, int out_size, void* d_ws, size_t ws_size,
                              hipStream_t stream) {
  const int*   q      = (const int*)d_in[0];
  const int*   dpos   = (const int*)d_in[1];
  const int*   dneg   = (const int*)d_in[2];
  const float* qmask  = (const float*)d_in[3];
  const float* dpmask = (const float*)d_in[4];
  const float* dnmask = (const float*)d_in[5];
  const int*   peflag = (const int*)d_in[6];
  const float* emb    = (const float*)d_in[7];
  const float* Wlin   = (const float*)d_in[8];
  const float* Wout   = (const float*)d_in[9];
  float* out = (float*)d_out;

  // allow 128 KB dynamic LDS (first call is uncaptured; attribute persists)
  (void)hipFuncSetAttribute(reinterpret_cast<const void*>(&gemm_mfma<false>),
                            hipFuncAttributeMaxDynamicSharedMemorySize, 131072);
  (void)hipFuncSetAttribute(reinterpret_cast<const void*>(&gemm_mfma<true>),
                            hipFuncAttributeMaxDynamicSharedMemorySize, 131072);

  char* ws = (char*)d_ws;
  size_t off = 0;
  auto alloc = [&](size_t bytes) -> char* {
    char* p = ws + off; off += (bytes + 255) & ~(size_t)255; return p;
  };
  __hip_bfloat16* Xq   = (__hip_bfloat16*)alloc((size_t)512 * DIM * 2);  // 480 rows + tile pad
  float*          Qsc  = (float*)         alloc((size_t)B_ * LQ * DIM * 4);
  __hip_bfloat16* Wl16 = (__hip_bfloat16*)alloc((size_t)DIM * DIM * 2);
  __hip_bfloat16* Wo16 = (__hip_bfloat16*)alloc((size_t)DIM * DIM * 2);

  // slots per chunk: all 32 (both docs) if ws allows; else halve.
  // buffers tile-padded (+256 rows) so gemm A-overreads stay in-bounds.
  int SC = NSLOT;
  while (SC > 1) {
    size_t need = off
        + ((size_t)SC * LD + 256) * DIM * 2 * 2                 // X + Y
        + ((size_t)SC * WNUM * LQ + 256) * DIM * 2 + (1u << 20);// ctx
    if (need <= ws_size) break;
    SC >>= 1;
  }
  __hip_bfloat16* X   = (__hip_bfloat16*)alloc(((size_t)SC * LD + 256) * DIM * 2);
  __hip_bfloat16* Y   = (__hip_bfloat16*)alloc(((size_t)SC * LD + 256) * DIM * 2);
  __hip_bfloat16* ctx = (__hip_bfloat16*)alloc(((size_t)SC * WNUM * LQ + 256) * DIM * 2);

  wconv_kernel<<<(DIM * DIM / 4 + 255) / 256, 256, 0, stream>>>(Wlin, Wout, Wl16, Wo16);
  prep_q_kernel<<<(B_ * LQ * (DIM / 4) + 255) / 256, 256, 0, stream>>>(q, qmask, emb, Xq);

  const int tilesX = DIM / 256;                       // 3
  const int qTiles = tilesX * ((B_ * LQ + 255) / 256);// 6 (Q-problem blocks)

  for (int s0 = 0; s0 < NSLOT; s0 += SC) {
    const int rowsX = SC * LD;           // 35200 at SC=32
    const int rowsC = SC * WNUM * LQ;    // 96000 at SC=32
    prep_d_kernel<<<(rowsX * (DIM / 4) + 255) / 256, 256, 0, stream>>>(
        dpos, dneg, dpmask, dnmask, emb, peflag, X, s0, rowsX);
    {
      // GEMM1 (+ fused Q-GEMM tail blocks on the first chunk)
      int tiles1 = tilesX * ((rowsX + 255) / 256);
      int t2 = (s0 == 0) ? qTiles : 0;
      gemm_mfma<true><<<tiles1 + t2, 512, 131072, stream>>>(
          X, Wl16, Y, rowsX, DIM, DIM, tilesX, tiles1, Xq, Qsc, B_ * LQ);
    }
    attn_kernel<<<SC * WNUM * NH, 120, 0, stream>>>(Qsc, Y, ctx, s0);
    {
      int tiles1 = tilesX * ((rowsC + 255) / 256);
      gemm_mfma<false><<<tiles1, 512, 131072, stream>>>(
          ctx, Wo16, out + (size_t)s0 * WNUM * LQ * DIM, rowsC, DIM, DIM,
          tilesX, tiles1, nullptr, nullptr, 0);
    }
  }
}